// Round 1
// baseline (889.687 us; speedup 1.0000x reference)
//
#include <hip/hip_runtime.h>

#define NEG_SLOPE 0.2f

__device__ __forceinline__ unsigned f2ord(float f) {
    unsigned u = __float_as_uint(f);
    return (u & 0x80000000u) ? ~u : (u | 0x80000000u);
}
__device__ __forceinline__ float ord2f(unsigned o) {
    unsigned u = (o & 0x80000000u) ? (o & 0x7FFFFFFFu) : ~o;
    return __uint_as_float(u);
}

// k1: h1 = x @ W1 (128x128) + per-node attention logits (2 heads x 64)
// 8 nodes per block, 128 threads; thread t owns output channel t.
__global__ __launch_bounds__(128) void k_gemm1(
    const float* __restrict__ x, const float* __restrict__ W1,
    const float* __restrict__ as1, const float* __restrict__ ad1,
    float* __restrict__ h1, float* __restrict__ alsrc, float* __restrict__ aldst,
    int N) {
    __shared__ float xs[8][128];
    int t = threadIdx.x;
    int n0 = blockIdx.x * 8;
#pragma unroll
    for (int j = 0; j < 8; j++) {
        int n = n0 + j;
        xs[j][t] = (n < N) ? x[(size_t)n * 128 + t] : 0.f;
    }
    __syncthreads();
    float acc[8];
#pragma unroll
    for (int j = 0; j < 8; j++) acc[j] = 0.f;
    for (int k = 0; k < 128; k++) {
        float w = W1[k * 128 + t];
#pragma unroll
        for (int j = 0; j < 8; j++) acc[j] = fmaf(xs[j][k], w, acc[j]);
    }
    int h = t >> 6, c = t & 63;
    float asv = as1[t];  // att_src1 is [2][64], index h*64+c == t
    float adv = ad1[t];
#pragma unroll
    for (int j = 0; j < 8; j++) {
        int n = n0 + j;
        if (n < N) h1[(size_t)n * 128 + t] = acc[j];
        float vs = acc[j] * asv, vd = acc[j] * adv;
#pragma unroll
        for (int o = 32; o > 0; o >>= 1) {
            vs += __shfl_down(vs, o);
            vd += __shfl_down(vd, o);
        }
        if (c == 0 && n < N) {
            alsrc[n * 2 + h] = vs;
            aldst[n * 2 + h] = vd;
        }
    }
}

// k6: h2 = hf @ W2 (128x40) + per-node attention logits (1 head x 40)
// 4 nodes per block (one per wave), 256 threads.
__global__ __launch_bounds__(256) void k_gemm2(
    const float* __restrict__ hf, const float* __restrict__ W2,
    const float* __restrict__ as2, const float* __restrict__ ad2,
    float* __restrict__ h2, float* __restrict__ alsrc, float* __restrict__ aldst,
    int N) {
    __shared__ float xs[4][128];
    int wave = threadIdx.x >> 6, lane = threadIdx.x & 63;
    int n = blockIdx.x * 4 + wave;
    if (n < N) {
        xs[wave][lane] = hf[(size_t)n * 128 + lane];
        xs[wave][lane + 64] = hf[(size_t)n * 128 + lane + 64];
    }
    __syncthreads();
    float acc = 0.f;
    if (n < N && lane < 40) {
#pragma unroll 16
        for (int k = 0; k < 128; k++) acc = fmaf(xs[wave][k], W2[k * 40 + lane], acc);
        h2[(size_t)n * 40 + lane] = acc;
    }
    float vs = (n < N && lane < 40) ? acc * as2[lane] : 0.f;
    float vd = (n < N && lane < 40) ? acc * ad2[lane] : 0.f;
#pragma unroll
    for (int o = 32; o > 0; o >>= 1) {
        vs += __shfl_down(vs, o);
        vd += __shfl_down(vd, o);
    }
    if (lane == 0 && n < N) {
        alsrc[n] = vs;
        aldst[n] = vd;
    }
}

// ---- layer 1 edge kernels (H=2) ----
__global__ void k_max1(const int* __restrict__ ei, const float* __restrict__ alsrc,
                       const float* __restrict__ aldst, unsigned* __restrict__ m1,
                       int E, int ET) {
    int e = blockIdx.x * blockDim.x + threadIdx.x;
    if (e >= ET) return;
    int s = (e < E) ? ei[e] : e - E;
    int d = (e < E) ? ei[E + e] : e - E;
#pragma unroll
    for (int h = 0; h < 2; h++) {
        float l = alsrc[s * 2 + h] + aldst[d * 2 + h];
        l = (l > 0.f) ? l : NEG_SLOPE * l;
        atomicMax(&m1[(size_t)d * 2 + h], f2ord(l));
    }
}

__global__ void k_ord2f(unsigned* m, int n) {
    int i = blockIdx.x * blockDim.x + threadIdx.x;
    if (i < n) ((float*)m)[i] = ord2f(m[i]);
}

__global__ void k_exp1(const int* __restrict__ ei, const float* __restrict__ alsrc,
                       const float* __restrict__ aldst, const float* __restrict__ m1,
                       float* __restrict__ s1, float* __restrict__ e1, int E, int ET) {
    int e = blockIdx.x * blockDim.x + threadIdx.x;
    if (e >= ET) return;
    int s = (e < E) ? ei[e] : e - E;
    int d = (e < E) ? ei[E + e] : e - E;
#pragma unroll
    for (int h = 0; h < 2; h++) {
        float l = alsrc[s * 2 + h] + aldst[d * 2 + h];
        l = (l > 0.f) ? l : NEG_SLOPE * l;
        float ev = __expf(l - m1[d * 2 + h]);
        e1[(size_t)e * 2 + h] = ev;
        atomicAdd(&s1[(size_t)d * 2 + h], ev);
    }
}

// 128 consecutive threads handle one edge (one channel each)
__global__ void k_acc1(const int* __restrict__ ei, const float* __restrict__ h1,
                       const float* __restrict__ e1, float* __restrict__ acc1,
                       int E, int ET) {
    size_t idx = (size_t)blockIdx.x * blockDim.x + threadIdx.x;
    int e = (int)(idx >> 7);
    if (e >= ET) return;
    int t = (int)(idx & 127);
    int s = (e < E) ? ei[e] : e - E;
    int d = (e < E) ? ei[E + e] : e - E;
    float ev = e1[(size_t)e * 2 + (t >> 6)];
    atomicAdd(&acc1[(size_t)d * 128 + t], ev * h1[(size_t)s * 128 + t]);
}

__global__ void k_fin1(const float* __restrict__ acc1, const float* __restrict__ s1,
                       const float* __restrict__ b1, float* __restrict__ hf, int N) {
    int idx = blockIdx.x * blockDim.x + threadIdx.x;
    if (idx >= N * 128) return;
    int n = idx >> 7, t = idx & 127;
    float v = acc1[idx] / (s1[n * 2 + (t >> 6)] + 1e-16f) + b1[t];
    hf[idx] = (v > 0.f) ? v : expm1f(v);  // ELU
}

// ---- layer 2 edge kernels (H=1, C=40) ----
__global__ void k_max2(const int* __restrict__ ei, const float* __restrict__ alsrc,
                       const float* __restrict__ aldst, unsigned* __restrict__ m2,
                       int E, int ET) {
    int e = blockIdx.x * blockDim.x + threadIdx.x;
    if (e >= ET) return;
    int s = (e < E) ? ei[e] : e - E;
    int d = (e < E) ? ei[E + e] : e - E;
    float l = alsrc[s] + aldst[d];
    l = (l > 0.f) ? l : NEG_SLOPE * l;
    atomicMax(&m2[d], f2ord(l));
}

__global__ void k_exp2(const int* __restrict__ ei, const float* __restrict__ alsrc,
                       const float* __restrict__ aldst, const float* __restrict__ m2,
                       float* __restrict__ s2, float* __restrict__ e2, int E, int ET) {
    int e = blockIdx.x * blockDim.x + threadIdx.x;
    if (e >= ET) return;
    int s = (e < E) ? ei[e] : e - E;
    int d = (e < E) ? ei[E + e] : e - E;
    float l = alsrc[s] + aldst[d];
    l = (l > 0.f) ? l : NEG_SLOPE * l;
    float ev = __expf(l - m2[d]);
    e2[e] = ev;
    atomicAdd(&s2[d], ev);
}

// 64 consecutive threads per edge, lanes 40..63 idle
__global__ void k_acc2(const int* __restrict__ ei, const float* __restrict__ h2,
                       const float* __restrict__ e2, float* __restrict__ acc2,
                       int E, int ET) {
    size_t idx = (size_t)blockIdx.x * blockDim.x + threadIdx.x;
    int e = (int)(idx >> 6);
    if (e >= ET) return;
    int c = (int)(idx & 63);
    if (c >= 40) return;
    int s = (e < E) ? ei[e] : e - E;
    int d = (e < E) ? ei[E + e] : e - E;
    atomicAdd(&acc2[(size_t)d * 40 + c], e2[e] * h2[(size_t)s * 40 + c]);
}

__global__ void k_fin2(const float* __restrict__ acc2, const float* __restrict__ s2,
                       const float* __restrict__ b2, float* __restrict__ out, int N) {
    int idx = blockIdx.x * blockDim.x + threadIdx.x;
    if (idx >= N * 40) return;
    int n = idx / 40, c = idx - n * 40;
    out[idx] = acc2[idx] / (s2[n] + 1e-16f) + b2[c];
}

extern "C" void kernel_launch(void* const* d_in, const int* in_sizes, int n_in,
                              void* d_out, int out_size, void* d_ws, size_t ws_size,
                              hipStream_t stream) {
    const float* x   = (const float*)d_in[0];
    const int*   ei  = (const int*)d_in[1];
    const float* W1  = (const float*)d_in[2];
    const float* as1 = (const float*)d_in[3];
    const float* ad1 = (const float*)d_in[4];
    const float* b1  = (const float*)d_in[5];
    const float* W2  = (const float*)d_in[6];
    const float* as2 = (const float*)d_in[7];
    const float* ad2 = (const float*)d_in[8];
    const float* b2  = (const float*)d_in[9];
    int N = in_sizes[0] / 128;
    int E = in_sizes[1] / 2;
    int ET = E + N;  // edges + self loops
    float* out = (float*)d_out;

    float* ws = (float*)d_ws;
    size_t off = 0;
    auto alloc = [&](size_t nfl) { float* p = ws + off; off += nfl; return p; };
    // zero-init region (one memset): max/sum/acc for both layers
    float* m1   = alloc((size_t)N * 2);
    float* s1   = alloc((size_t)N * 2);
    float* acc1 = alloc((size_t)N * 128);
    float* m2   = alloc((size_t)N);
    float* s2   = alloc((size_t)N);
    float* acc2 = alloc((size_t)N * 40);
    size_t zf = off;
    // no-init region
    float* h1     = alloc((size_t)N * 128);
    float* alsrc1 = alloc((size_t)N * 2);
    float* aldst1 = alloc((size_t)N * 2);
    float* e1     = alloc((size_t)ET * 2);
    float* h2     = alloc((size_t)N * 40);
    float* alsrc2 = alloc((size_t)N);
    float* aldst2 = alloc((size_t)N);
    float* e2     = alloc((size_t)ET);
    float* hf     = h1;  // post-ELU features reuse h1 (dead after k_acc1)

    hipMemsetAsync(ws, 0, zf * sizeof(float), stream);

    dim3 b256(256);
    int gE = (ET + 255) / 256;

    // layer 1
    k_gemm1<<<dim3((N + 7) / 8), dim3(128), 0, stream>>>(x, W1, as1, ad1, h1, alsrc1, aldst1, N);
    k_max1<<<gE, b256, 0, stream>>>(ei, alsrc1, aldst1, (unsigned*)m1, E, ET);
    k_ord2f<<<(N * 2 + 255) / 256, b256, 0, stream>>>((unsigned*)m1, N * 2);
    k_exp1<<<gE, b256, 0, stream>>>(ei, alsrc1, aldst1, m1, s1, e1, E, ET);
    k_acc1<<<(int)(((size_t)ET * 128 + 255) / 256), b256, 0, stream>>>(ei, h1, e1, acc1, E, ET);
    k_fin1<<<(N * 128 + 255) / 256, b256, 0, stream>>>(acc1, s1, b1, hf, N);
    // layer 2
    k_gemm2<<<(N + 3) / 4, b256, 0, stream>>>(hf, W2, as2, ad2, h2, alsrc2, aldst2, N);
    k_max2<<<gE, b256, 0, stream>>>(ei, alsrc2, aldst2, (unsigned*)m2, E, ET);
    k_ord2f<<<(N + 255) / 256, b256, 0, stream>>>((unsigned*)m2, N);
    k_exp2<<<gE, b256, 0, stream>>>(ei, alsrc2, aldst2, m2, s2, e2, E, ET);
    k_acc2<<<(int)(((size_t)ET * 64 + 255) / 256), b256, 0, stream>>>(ei, h2, e2, acc2, E, ET);
    k_fin2<<<(N * 40 + 255) / 256, b256, 0, stream>>>(acc2, s2, b2, out, N);
}

// Round 2
// 327.456 us; speedup vs baseline: 2.7170x; 2.7170x over previous
//
#include <hip/hip_runtime.h>

#define NEG_SLOPE 0.2f

// ---------------- GEMM1: h1 = x @ W1 (128x128) + attention logits ----------------
__global__ __launch_bounds__(128) void k_gemm1(
    const float* __restrict__ x, const float* __restrict__ W1,
    const float* __restrict__ as1, const float* __restrict__ ad1,
    float* __restrict__ h1, float* __restrict__ alsrc, float* __restrict__ aldst,
    int N) {
    __shared__ float xs[8][128];
    int t = threadIdx.x;
    int n0 = blockIdx.x * 8;
#pragma unroll
    for (int j = 0; j < 8; j++) {
        int n = n0 + j;
        xs[j][t] = (n < N) ? x[(size_t)n * 128 + t] : 0.f;
    }
    __syncthreads();
    float acc[8];
#pragma unroll
    for (int j = 0; j < 8; j++) acc[j] = 0.f;
    for (int k = 0; k < 128; k++) {
        float w = W1[k * 128 + t];
#pragma unroll
        for (int j = 0; j < 8; j++) acc[j] = fmaf(xs[j][k], w, acc[j]);
    }
    int h = t >> 6, c = t & 63;
    float asv = as1[t];
    float adv = ad1[t];
#pragma unroll
    for (int j = 0; j < 8; j++) {
        int n = n0 + j;
        if (n < N) h1[(size_t)n * 128 + t] = acc[j];
        float vs = acc[j] * asv, vd = acc[j] * adv;
#pragma unroll
        for (int o = 32; o > 0; o >>= 1) {
            vs += __shfl_down(vs, o);
            vd += __shfl_down(vd, o);
        }
        if (c == 0 && n < N) {
            alsrc[n * 2 + h] = vs;
            aldst[n * 2 + h] = vd;
        }
    }
}

// ---------------- GEMM2: h2 = hf @ W2 (128x40) + attention logits ----------------
__global__ __launch_bounds__(256) void k_gemm2(
    const float* __restrict__ hf, const float* __restrict__ W2,
    const float* __restrict__ as2, const float* __restrict__ ad2,
    float* __restrict__ h2, float* __restrict__ alsrc, float* __restrict__ aldst,
    int N) {
    __shared__ float xs[4][128];
    int wave = threadIdx.x >> 6, lane = threadIdx.x & 63;
    int n = blockIdx.x * 4 + wave;
    if (n < N) {
        xs[wave][lane] = hf[(size_t)n * 128 + lane];
        xs[wave][lane + 64] = hf[(size_t)n * 128 + lane + 64];
    }
    __syncthreads();
    float acc = 0.f;
    if (n < N && lane < 40) {
#pragma unroll 16
        for (int k = 0; k < 128; k++) acc = fmaf(xs[wave][k], W2[k * 40 + lane], acc);
        h2[(size_t)n * 40 + lane] = acc;
    }
    float vs = (n < N && lane < 40) ? acc * as2[lane] : 0.f;
    float vd = (n < N && lane < 40) ? acc * ad2[lane] : 0.f;
#pragma unroll
    for (int o = 32; o > 0; o >>= 1) {
        vs += __shfl_down(vs, o);
        vd += __shfl_down(vd, o);
    }
    if (lane == 0 && n < N) {
        alsrc[n] = vs;
        aldst[n] = vd;
    }
}

// ---------------- CSR build: count -> scan (3 kernels) -> scatter ----------------
__global__ void k_count(const int* __restrict__ ei, int* __restrict__ cnt, int E, int ET) {
    int e = blockIdx.x * blockDim.x + threadIdx.x;
    if (e >= ET) return;
    int d = (e < E) ? ei[E + e] : e - E;
    atomicAdd(&cnt[d], 1);
}

// per-tile (256) inclusive scan; tile total to sums[b]
__global__ __launch_bounds__(256) void k_scan1(const int* __restrict__ cnt,
                                               int* __restrict__ loc,
                                               int* __restrict__ sums, int N) {
    __shared__ int sh[256];
    int i = blockIdx.x * 256 + threadIdx.x;
    int v = (i < N) ? cnt[i] : 0;
    sh[threadIdx.x] = v;
    __syncthreads();
    for (int o = 1; o < 256; o <<= 1) {
        int t = (threadIdx.x >= o) ? sh[threadIdx.x - o] : 0;
        __syncthreads();
        sh[threadIdx.x] += t;
        __syncthreads();
    }
    if (i < N) loc[i] = sh[threadIdx.x];
    if (threadIdx.x == 255) sums[blockIdx.x] = sh[255];
}

// exclusive scan of tile sums (nb <= 256), single block
__global__ __launch_bounds__(256) void k_scan2(int* __restrict__ sums, int nb) {
    __shared__ int sh[256];
    int v = (threadIdx.x < nb) ? sums[threadIdx.x] : 0;
    sh[threadIdx.x] = v;
    __syncthreads();
    for (int o = 1; o < 256; o <<= 1) {
        int t = (threadIdx.x >= o) ? sh[threadIdx.x - o] : 0;
        __syncthreads();
        sh[threadIdx.x] += t;
        __syncthreads();
    }
    if (threadIdx.x < nb) sums[threadIdx.x] = sh[threadIdx.x] - v;  // exclusive
}

// rowptr[i] = sums_ex[blk] + loc[i] - cnt[i]; also duplicate into woff
__global__ __launch_bounds__(256) void k_scan3(const int* __restrict__ cnt,
                                               const int* __restrict__ loc,
                                               const int* __restrict__ sums,
                                               int* __restrict__ rowptr,
                                               int* __restrict__ woff, int N, int ET) {
    int i = blockIdx.x * 256 + threadIdx.x;
    if (i == 0) rowptr[N] = ET;
    if (i >= N) return;
    int v = sums[blockIdx.x] + loc[i] - cnt[i];
    rowptr[i] = v;
    woff[i] = v;
}

__global__ void k_scatter(const int* __restrict__ ei, int* __restrict__ woff,
                          int* __restrict__ col, int E, int ET) {
    int e = blockIdx.x * blockDim.x + threadIdx.x;
    if (e >= ET) return;
    int s = (e < E) ? ei[e] : e - E;
    int d = (e < E) ? ei[E + e] : e - E;
    int pos = atomicAdd(&woff[d], 1);
    col[pos] = s;
}

// ---------------- fused gather layer 1: softmax + aggregate + bias + ELU ----------------
// one wave per dst node; lane owns channels {lane, lane+64}
__global__ __launch_bounds__(256) void k_gather1(
    const int* __restrict__ rowptr, const int* __restrict__ col,
    const float* __restrict__ h1, const float* __restrict__ alsrc,
    const float* __restrict__ aldst, const float* __restrict__ b1,
    float* __restrict__ hf, int N) {
    int wid = (int)(((size_t)blockIdx.x * blockDim.x + threadIdx.x) >> 6);
    int lane = threadIdx.x & 63;
    if (wid >= N) return;
    int n = wid;
    int start = rowptr[n], end = rowptr[n + 1];
    float ad0 = aldst[n * 2], ad1 = aldst[n * 2 + 1];
    float m0 = -1e30f, m1 = -1e30f, s0 = 0.f, s1 = 0.f, a0 = 0.f, a1 = 0.f;
    for (int base = start; base < end; base += 64) {
        int nb = min(64, end - base);
        int sv = 0;
        float l0v = 0.f, l1v = 0.f;
        if (lane < nb) {
            sv = col[base + lane];
            float t0 = alsrc[sv * 2] + ad0;
            float t1 = alsrc[sv * 2 + 1] + ad1;
            l0v = (t0 > 0.f) ? t0 : NEG_SLOPE * t0;
            l1v = (t1 > 0.f) ? t1 : NEG_SLOPE * t1;
        }
        for (int j = 0; j < nb; j++) {
            int s = __shfl(sv, j);
            float l0 = __shfl(l0v, j), l1 = __shfl(l1v, j);
            float h0 = h1[(size_t)s * 128 + lane];
            float h64 = h1[(size_t)s * 128 + 64 + lane];
            // online softmax, wave-uniform branches
            if (l0 > m0) {
                float sc = __expf(m0 - l0);
                s0 *= sc; a0 *= sc; m0 = l0;
            }
            if (l1 > m1) {
                float sc = __expf(m1 - l1);
                s1 *= sc; a1 *= sc; m1 = l1;
            }
            float e0 = __expf(l0 - m0), e1 = __expf(l1 - m1);
            s0 += e0; a0 = fmaf(e0, h0, a0);
            s1 += e1; a1 = fmaf(e1, h64, a1);
        }
    }
    float v0 = a0 / (s0 + 1e-16f) + b1[lane];
    float v1 = a1 / (s1 + 1e-16f) + b1[64 + lane];
    hf[(size_t)n * 128 + lane] = (v0 > 0.f) ? v0 : expm1f(v0);
    hf[(size_t)n * 128 + 64 + lane] = (v1 > 0.f) ? v1 : expm1f(v1);
}

// ---------------- fused gather layer 2: softmax + aggregate + bias -> out ----------------
__global__ __launch_bounds__(256) void k_gather2(
    const int* __restrict__ rowptr, const int* __restrict__ col,
    const float* __restrict__ h2, const float* __restrict__ alsrc,
    const float* __restrict__ aldst, const float* __restrict__ b2,
    float* __restrict__ out, int N) {
    int wid = (int)(((size_t)blockIdx.x * blockDim.x + threadIdx.x) >> 6);
    int lane = threadIdx.x & 63;
    if (wid >= N) return;
    int n = wid;
    int start = rowptr[n], end = rowptr[n + 1];
    float ad = aldst[n];
    float m = -1e30f, s = 0.f, a = 0.f;
    for (int base = start; base < end; base += 64) {
        int nb = min(64, end - base);
        int sv = 0;
        float lv = 0.f;
        if (lane < nb) {
            sv = col[base + lane];
            float t = alsrc[sv] + ad;
            lv = (t > 0.f) ? t : NEG_SLOPE * t;
        }
        for (int j = 0; j < nb; j++) {
            int src = __shfl(sv, j);
            float l = __shfl(lv, j);
            float hv = (lane < 40) ? h2[(size_t)src * 40 + lane] : 0.f;
            if (l > m) {
                float sc = __expf(m - l);
                s *= sc; a *= sc; m = l;
            }
            float e = __expf(l - m);
            s += e; a = fmaf(e, hv, a);
        }
    }
    if (lane < 40) out[(size_t)n * 40 + lane] = a / (s + 1e-16f) + b2[lane];
}

extern "C" void kernel_launch(void* const* d_in, const int* in_sizes, int n_in,
                              void* d_out, int out_size, void* d_ws, size_t ws_size,
                              hipStream_t stream) {
    const float* x   = (const float*)d_in[0];
    const int*   ei  = (const int*)d_in[1];
    const float* W1  = (const float*)d_in[2];
    const float* as1 = (const float*)d_in[3];
    const float* ad1 = (const float*)d_in[4];
    const float* b1  = (const float*)d_in[5];
    const float* W2  = (const float*)d_in[6];
    const float* as2 = (const float*)d_in[7];
    const float* ad2 = (const float*)d_in[8];
    const float* b2  = (const float*)d_in[9];
    int N = in_sizes[0] / 128;
    int E = in_sizes[1] / 2;
    int ET = E + N;
    float* out = (float*)d_out;

    char* ws = (char*)d_ws;
    size_t off = 0;
    auto alloc = [&](size_t bytes) {
        char* p = ws + off;
        off += (bytes + 255) & ~(size_t)255;
        return p;
    };
    int nb = (N + 255) / 256;
    int*   cnt    = (int*)alloc((size_t)N * 4);          // zero-init
    int*   loc    = (int*)alloc((size_t)N * 4);
    int*   sums   = (int*)alloc(256 * 4);
    int*   rowptr = (int*)alloc(((size_t)N + 1) * 4);
    int*   woff   = (int*)alloc((size_t)N * 4);
    int*   colbuf = (int*)alloc((size_t)ET * 4);
    float* h1     = (float*)alloc((size_t)N * 128 * 4);
    float* hf     = (float*)alloc((size_t)N * 128 * 4);
    float* h2     = (float*)alloc((size_t)N * 40 * 4);
    float* alsrc1 = (float*)alloc((size_t)N * 2 * 4);
    float* aldst1 = (float*)alloc((size_t)N * 2 * 4);
    float* alsrc2 = (float*)alloc((size_t)N * 4);
    float* aldst2 = (float*)alloc((size_t)N * 4);

    hipMemsetAsync(cnt, 0, (size_t)N * 4, stream);

    dim3 b256(256);
    int gE = (ET + 255) / 256;

    // CSR build (shared by both layers)
    k_count<<<gE, b256, 0, stream>>>(ei, cnt, E, ET);
    k_scan1<<<nb, b256, 0, stream>>>(cnt, loc, sums, N);
    k_scan2<<<1, b256, 0, stream>>>(sums, nb);
    k_scan3<<<nb, b256, 0, stream>>>(cnt, loc, sums, rowptr, woff, N, ET);
    k_scatter<<<gE, b256, 0, stream>>>(ei, woff, colbuf, E, ET);

    // layer 1
    k_gemm1<<<dim3((N + 7) / 8), dim3(128), 0, stream>>>(x, W1, as1, ad1, h1, alsrc1, aldst1, N);
    k_gather1<<<(int)(((size_t)N * 64 + 255) / 256), b256, 0, stream>>>(
        rowptr, colbuf, h1, alsrc1, aldst1, b1, hf, N);

    // layer 2
    k_gemm2<<<(N + 3) / 4, b256, 0, stream>>>(hf, W2, as2, ad2, h2, alsrc2, aldst2, N);
    k_gather2<<<(int)(((size_t)N * 64 + 255) / 256), b256, 0, stream>>>(
        rowptr, colbuf, h2, alsrc2, aldst2, b2, out, N);
}